// Round 4
// baseline (1768.474 us; speedup 1.0000x reference)
//
#include <hip/hip_runtime.h>
#include <math.h>

#define L 2048
#define D 64
#define MT 64        // query rows per block
#define KT 128       // keys per tile
#define NT 512       // threads (8 waves)
#define CNT 256      // prekernel threads
#define NTILE (L / KT)

typedef _Float16 halfx8 __attribute__((ext_vector_type(8)));
typedef _Float16 halfx4 __attribute__((ext_vector_type(4)));
typedef float f32x4  __attribute__((ext_vector_type(4)));
typedef int   i32x4  __attribute__((ext_vector_type(4)));

#define MFMA16 __builtin_amdgcn_mfma_f32_16x16x32_f16

// ---------- prekernel 1: fp32 rows -> f16, 16B chunks XOR-swizzled by row ----
__global__ __launch_bounds__(CNT) void conv_swz(
    const float* __restrict__ src, _Float16* __restrict__ dst, int nrows)
{
    int g = blockIdx.x * CNT + threadIdx.x;     // one 16B output chunk
    if (g >= nrows * 8) return;
    int row = g >> 3, c = g & 7;
    const float4* s4 = (const float4*)(src + (size_t)row * D + c * 8);
    float4 a = s4[0], b = s4[1];
    halfx8 t;
    t[0]=(_Float16)a.x; t[1]=(_Float16)a.y; t[2]=(_Float16)a.z; t[3]=(_Float16)a.w;
    t[4]=(_Float16)b.x; t[5]=(_Float16)b.y; t[6]=(_Float16)b.z; t[7]=(_Float16)b.w;
    *(halfx8*)(dst + (size_t)row * D + ((c ^ (row & 7)) * 8)) = t;
}

// ---------- prekernel 2: V -> Vt tiles [head][kt][d][key] f16, swizzled ----
__global__ __launch_bounds__(CNT) void vtrans(
    const float* __restrict__ v, _Float16* __restrict__ vt)
{
    const int h  = blockIdx.x >> 4;
    const int kt = blockIdx.x & 15;
    const float* src = v + ((size_t)h * L + (size_t)kt * KT) * D;
    _Float16* dst = vt + (size_t)blockIdx.x * (D * KT);
    __shared__ _Float16 Vs[KT * 68];
    const int t = threadIdx.x;
    {
        const int r = t & 127, seg = t >> 7;
        const float4* s4 = (const float4*)(src + r * D + seg * 32);
        #pragma unroll
        for (int kq = 0; kq < 8; ++kq) {
            float4 a = s4[kq];
            halfx4 b;
            b[0]=(_Float16)a.x; b[1]=(_Float16)a.y; b[2]=(_Float16)a.z; b[3]=(_Float16)a.w;
            *(halfx4*)(Vs + r * 68 + seg * 32 + kq * 4) = b;
        }
    }
    __syncthreads();
    #pragma unroll
    for (int j = 0; j < 4; ++j) {
        const int cg = t + CNT * j;
        const int d = cg >> 4, c = cg & 15;
        halfx8 o;
        #pragma unroll
        for (int jj = 0; jj < 8; ++jj) o[jj] = Vs[(c * 8 + jj) * 68 + d];
        *(halfx8*)(dst + d * KT + ((c ^ (d & 7)) * 8)) = o;
    }
}

// ---------- main: phase A (sums + O) -> phase C (recompute S, write attn once) ----
// S^T = K.Q^T so lane holds 4 consecutive keys -> int4 mask loads (cached, once;
// bits register-packed for phase C), float4 attn stores (cached, once, normalized).
// NOTE: all loads/stores deliberately CACHED — nontemporal hints on the scattered
// 64B row-segments caused ~4x HBM RMW amplification in round 3 (FETCH 2.1 GB).
__global__ __launch_bounds__(NT, 6) void sdpa_fused(
    const _Float16* __restrict__ kb,
    const _Float16* __restrict__ vtb,
    const float*    __restrict__ q,
    const int*      __restrict__ mask,
    float* __restrict__ out,
    float* __restrict__ attn)
{
    const int bid0 = blockIdx.x;                 // 1024
    const int bid  = (bid0 & 7) * 128 + (bid0 >> 3);   // XCD swizzle (1024%8==0)
    const int bn   = bid >> 5;                   // head 0..31
    const int qt   = bid & 31;
    const int row0 = qt * MT;
    const int tid  = threadIdx.x;
    const int wave = tid >> 6;                   // 0..7
    const int lane = tid & 63;
    const int lq   = lane & 15;
    const int lg   = lane >> 4;
    const int swz  = lq & 7;

    __shared__ __align__(16) char smem[49152];   // 48 KB -> 3 blocks/CU
    _Float16* Kb = (_Float16*)smem;              // 128 keys x 64 d  (16 KB)
    _Float16* Vb = (_Float16*)(smem + 16384);    // 64 d x 128 keys  (16 KB)
    _Float16* Ps = (_Float16*)(smem + 32768);    // 64 q x 128 keys  (16 KB)
    _Float16* Qt = Ps;                           // prologue alias (8 KB)
    float* sums_w = (float*)(smem + 32768);      // [8][64] post-loop alias
    float* inv_l  = (float*)(smem + 32768 + 2048);

    const _Float16* kh = kb  + (size_t)bn * (L * D);
    const _Float16* vh = vtb + (size_t)bn * (L * D);
    const int*      mg = mask + ((size_t)bn * L + row0) * L;
    float*          ag = attn + ((size_t)bn * L + row0) * L;

    // ---- prologue: convert this block's 64 Q rows to f16 (swizzled) ----
    {
        const int r = tid >> 3, c = tid & 7;     // 64 rows x 8 chunks
        const float4* s4 = (const float4*)(q + ((size_t)bn * L + row0 + r) * D + c * 8);
        float4 a = s4[0], b = s4[1];
        halfx8 t;
        t[0]=(_Float16)a.x; t[1]=(_Float16)a.y; t[2]=(_Float16)a.z; t[3]=(_Float16)a.w;
        t[4]=(_Float16)b.x; t[5]=(_Float16)b.y; t[6]=(_Float16)b.z; t[7]=(_Float16)b.w;
        *(halfx8*)(Qt + r * D + ((c ^ (r & 7)) * 8)) = t;
    }
    __syncthreads();
    halfx8 qf[4][2];
    #pragma unroll
    for (int qq = 0; qq < 4; ++qq)
        #pragma unroll
        for (int s = 0; s < 2; ++s)
            qf[qq][s] = *(const halfx8*)(Qt + (qq*16 + lq) * D + (((s*4 + lg) ^ swz) * 8));
    __syncthreads();   // Qt reads done before Ps reuse

    f32x4 of[2] = {};
    float sumreg[4] = {0.f, 0.f, 0.f, 0.f};
    unsigned long long mpack[4] = {0ull, 0ull, 0ull, 0ull};  // 16 tiles x 4 bits

    // prefetch tile 0
    halfx8 kr0 = *(const halfx8*)(kh + tid * 8);
    halfx8 kr1 = *(const halfx8*)(kh + (NT + tid) * 8);
    halfx8 vr0 = *(const halfx8*)(vh + tid * 8);
    halfx8 vr1 = *(const halfx8*)(vh + (NT + tid) * 8);
    i32x4 m4[4], m4n[4];
    #pragma unroll
    for (int qq = 0; qq < 4; ++qq)
        m4[qq] = *(const i32x4*)(mg + (size_t)(qq*16 + lq) * L + wave*16 + lg*4);

    // ================= PHASE A: sums + O =================
    #pragma unroll 2
    for (int t = 0; t < NTILE; ++t) {
        const int kb0 = t * KT;
        __syncthreads();                          // B0: prev tile LDS readers done
        *(halfx8*)(Kb + tid * 8)        = kr0;
        *(halfx8*)(Kb + (NT + tid) * 8) = kr1;
        *(halfx8*)(Vb + tid * 8)        = vr0;
        *(halfx8*)(Vb + (NT + tid) * 8) = vr1;
        __syncthreads();                          // B1: tiles staged
        if (t + 1 < NTILE) {                      // prefetch t+1 (lands during compute)
            const _Float16* ks = kh + (size_t)(kb0 + KT) * D;
            const _Float16* vs = vh + (size_t)(t + 1) * (KT * D);
            kr0 = *(const halfx8*)(ks + tid * 8);
            kr1 = *(const halfx8*)(ks + (NT + tid) * 8);
            vr0 = *(const halfx8*)(vs + tid * 8);
            vr1 = *(const halfx8*)(vs + (NT + tid) * 8);
            #pragma unroll
            for (int qq = 0; qq < 4; ++qq)
                m4n[qq] = *(const i32x4*)(mg + (size_t)(qq*16 + lq) * L
                                             + (kb0 + KT) + wave*16 + lg*4);
        }

        // S^T tile: wave owns keys [wave*16, wave*16+16)
        f32x4 acc[4] = {};
        __builtin_amdgcn_s_setprio(1);
        #pragma unroll
        for (int s = 0; s < 2; ++s) {
            halfx8 a = *(const halfx8*)(Kb + (wave*16 + lq) * D + (((s*4 + lg) ^ swz) * 8));
            acc[0] = MFMA16(a, qf[0][s], acc[0], 0, 0, 0);
            acc[1] = MFMA16(a, qf[1][s], acc[1], 0, 0, 0);
            acc[2] = MFMA16(a, qf[2][s], acc[2], 0, 0, 0);
            acc[3] = MFMA16(a, qf[3][s], acc[3], 0, 0, 0);
        }
        __builtin_amdgcn_s_setprio(0);

        // mask -> pack bits; e = exp(S/8) -> Ps (f16) + fp32 row sums
        const int colL = wave*16 + lg*4;
        #pragma unroll
        for (int qq = 0; qq < 4; ++qq) {
            const int qrow = qq*16 + lq;
            const i32x4 m = m4[qq];
            const f32x4 a = acc[qq];
            const unsigned mm = (m[0]?1u:0u) | (m[1]?2u:0u) | (m[2]?4u:0u) | (m[3]?8u:0u);
            mpack[qq] |= (unsigned long long)mm << (t * 4);
            const float e0 = m[0] ? 0.f : __expf(a[0] * 0.125f);
            const float e1 = m[1] ? 0.f : __expf(a[1] * 0.125f);
            const float e2 = m[2] ? 0.f : __expf(a[2] * 0.125f);
            const float e3 = m[3] ? 0.f : __expf(a[3] * 0.125f);
            sumreg[qq] += (e0 + e1) + (e2 + e3);
            halfx4 pb;
            pb[0]=(_Float16)e0; pb[1]=(_Float16)e1; pb[2]=(_Float16)e2; pb[3]=(_Float16)e3;
            *(halfx4*)(Ps + qrow * KT + (colL ^ (swz << 3))) = pb;
        }
        if (t + 1 < NTILE) {
            #pragma unroll
            for (int qq = 0; qq < 4; ++qq) m4[qq] = m4n[qq];
        }
        __syncthreads();                          // B2: Ps ready

        // O += Ps @ Vt ; wave (wr,wc): q-rows [wr*32,+32), d-cols [wc*16,+16)
        const int wr = wave >> 2, wc = wave & 3;
        __builtin_amdgcn_s_setprio(1);
        #pragma unroll
        for (int s2 = 0; s2 < 4; ++s2) {
            const int ch = ((s2*4 + lg) ^ swz) * 8;
            halfx8 vb = *(const halfx8*)(Vb + (wc*16 + lq) * KT + ch);
            halfx8 p0 = *(const halfx8*)(Ps + (wr*32 + lq) * KT + ch);
            halfx8 p1 = *(const halfx8*)(Ps + (wr*32 + 16 + lq) * KT + ch);
            of[0] = MFMA16(p0, vb, of[0], 0, 0, 0);
            of[1] = MFMA16(p1, vb, of[1], 0, 0, 0);
        }
        __builtin_amdgcn_s_setprio(0);
    }

    // ---- row sums -> inv ----
    #pragma unroll
    for (int qq = 0; qq < 4; ++qq) {
        sumreg[qq] += __shfl_xor(sumreg[qq], 16, 64);
        sumreg[qq] += __shfl_xor(sumreg[qq], 32, 64);
    }
    __syncthreads();                              // last PV reads of Ps done
    if (lane < 16) {
        #pragma unroll
        for (int qq = 0; qq < 4; ++qq)
            sums_w[wave * 64 + qq*16 + lane] = sumreg[qq];
    }
    __syncthreads();
    if (tid < MT) {
        float s = 0.f;
        #pragma unroll
        for (int w = 0; w < 8; ++w) s += sums_w[w * 64 + tid];
        inv_l[tid] = 1.0f / s;
    }
    __syncthreads();

    // per-lane inv for the S^T layout (row = qq*16+lq)
    float invq[4];
    #pragma unroll
    for (int qq = 0; qq < 4; ++qq) invq[qq] = inv_l[qq*16 + lq];

    // phase-C prefetch tile 0 K (issue early, lands during O epilogue)
    kr0 = *(const halfx8*)(kh + tid * 8);
    kr1 = *(const halfx8*)(kh + (NT + tid) * 8);

    // ---- O epilogue (scaled) ----
    {
        const int wr = wave >> 2, wc = wave & 3;
        #pragma unroll
        for (int r = 0; r < 2; ++r)
            #pragma unroll
            for (int i = 0; i < 4; ++i) {
                const int qrow = wr*32 + r*16 + lg*4 + i;
                out[((size_t)bn * L + row0 + qrow) * D + wc*16 + lq] = of[r][i] * inv_l[qrow];
            }
    }

    // ================= PHASE C: recompute S, write normalized attn once ======
    const int colL = wave*16 + lg*4;
    #pragma unroll 2
    for (int t = 0; t < NTILE; ++t) {
        const int kb0 = t * KT;
        __syncthreads();                          // prev tile Kb readers done
        *(halfx8*)(Kb + tid * 8)        = kr0;
        *(halfx8*)(Kb + (NT + tid) * 8) = kr1;
        __syncthreads();                          // K staged
        if (t + 1 < NTILE) {
            const _Float16* ks = kh + (size_t)(kb0 + KT) * D;
            kr0 = *(const halfx8*)(ks + tid * 8);
            kr1 = *(const halfx8*)(ks + (NT + tid) * 8);
        }

        f32x4 acc[4] = {};
        __builtin_amdgcn_s_setprio(1);
        #pragma unroll
        for (int s = 0; s < 2; ++s) {
            halfx8 a = *(const halfx8*)(Kb + (wave*16 + lq) * D + (((s*4 + lg) ^ swz) * 8));
            acc[0] = MFMA16(a, qf[0][s], acc[0], 0, 0, 0);
            acc[1] = MFMA16(a, qf[1][s], acc[1], 0, 0, 0);
            acc[2] = MFMA16(a, qf[2][s], acc[2], 0, 0, 0);
            acc[3] = MFMA16(a, qf[3][s], acc[3], 0, 0, 0);
        }
        __builtin_amdgcn_s_setprio(0);

        #pragma unroll
        for (int qq = 0; qq < 4; ++qq) {
            const unsigned mm = (unsigned)(mpack[qq] >> (t * 4)) & 15u;
            const f32x4 a = acc[qq];
            const float inv = invq[qq];
            f32x4 ev;
            ev[0] = (mm & 1u) ? 0.f : __expf(a[0] * 0.125f) * inv;
            ev[1] = (mm & 2u) ? 0.f : __expf(a[1] * 0.125f) * inv;
            ev[2] = (mm & 4u) ? 0.f : __expf(a[2] * 0.125f) * inv;
            ev[3] = (mm & 8u) ? 0.f : __expf(a[3] * 0.125f) * inv;
            *(f32x4*)(ag + (size_t)(qq*16 + lq) * L + kb0 + colL) = ev;
        }
    }
}

extern "C" void kernel_launch(void* const* d_in, const int* in_sizes, int n_in,
                              void* d_out, int out_size, void* d_ws, size_t ws_size,
                              hipStream_t stream) {
    const float* q    = (const float*)d_in[0];
    const float* k    = (const float*)d_in[1];
    const float* v    = (const float*)d_in[2];
    const int*   mask = (const int*)d_in[3];

    float* out = (float*)d_out;
    const int rows = in_sizes[0] / D;              // B*N*L = 65536
    float* attn = out + (size_t)rows * D;

    // workspace: kb | vtb (f16) = ~16.8 MB
    _Float16* kbuf = (_Float16*)d_ws;
    _Float16* vtb  = kbuf + (size_t)rows * D;

    conv_swz<<<rows * 8 / CNT, CNT, 0, stream>>>(k, kbuf, rows);
    vtrans<<<(rows / L) * NTILE, CNT, 0, stream>>>(v, vtb);
    sdpa_fused<<<rows / MT, NT, 0, stream>>>(kbuf, vtb, q, mask, out, attn);
}

// Round 5
// 1550.402 us; speedup vs baseline: 1.1407x; 1.1407x over previous
//
#include <hip/hip_runtime.h>
#include <math.h>

#define L 2048
#define D 64
#define MT 64        // query rows per block
#define KT 128       // keys per tile
#define NT 512       // threads (8 waves)
#define CNT 256      // prekernel threads
#define NTILE (L / KT)

typedef _Float16 halfx8 __attribute__((ext_vector_type(8)));
typedef _Float16 halfx4 __attribute__((ext_vector_type(4)));
typedef float f32x4  __attribute__((ext_vector_type(4)));
typedef int   i32x4  __attribute__((ext_vector_type(4)));

#define MFMA16 __builtin_amdgcn_mfma_f32_16x16x32_f16

// ---------- prekernel 1: fp32 rows -> f16, 16B chunks XOR-swizzled by row ----
__global__ __launch_bounds__(CNT) void conv_swz(
    const float* __restrict__ src, _Float16* __restrict__ dst, int nrows)
{
    int g = blockIdx.x * CNT + threadIdx.x;     // one 16B output chunk
    if (g >= nrows * 8) return;
    int row = g >> 3, c = g & 7;
    const float4* s4 = (const float4*)(src + (size_t)row * D + c * 8);
    float4 a = s4[0], b = s4[1];
    halfx8 t;
    t[0]=(_Float16)a.x; t[1]=(_Float16)a.y; t[2]=(_Float16)a.z; t[3]=(_Float16)a.w;
    t[4]=(_Float16)b.x; t[5]=(_Float16)b.y; t[6]=(_Float16)b.z; t[7]=(_Float16)b.w;
    *(halfx8*)(dst + (size_t)row * D + ((c ^ (row & 7)) * 8)) = t;
}

// ---------- prekernel 2: V -> Vt tiles [head][kt][d][key] f16, swizzled ----
__global__ __launch_bounds__(CNT) void vtrans(
    const float* __restrict__ v, _Float16* __restrict__ vt)
{
    const int h  = blockIdx.x >> 4;
    const int kt = blockIdx.x & 15;
    const float* src = v + ((size_t)h * L + (size_t)kt * KT) * D;
    _Float16* dst = vt + (size_t)blockIdx.x * (D * KT);
    __shared__ _Float16 Vs[KT * 68];
    const int t = threadIdx.x;
    {
        const int r = t & 127, seg = t >> 7;
        const float4* s4 = (const float4*)(src + r * D + seg * 32);
        #pragma unroll
        for (int kq = 0; kq < 8; ++kq) {
            float4 a = s4[kq];
            halfx4 b;
            b[0]=(_Float16)a.x; b[1]=(_Float16)a.y; b[2]=(_Float16)a.z; b[3]=(_Float16)a.w;
            *(halfx4*)(Vs + r * 68 + seg * 32 + kq * 4) = b;
        }
    }
    __syncthreads();
    #pragma unroll
    for (int j = 0; j < 4; ++j) {
        const int cg = t + CNT * j;
        const int d = cg >> 4, c = cg & 15;
        halfx8 o;
        #pragma unroll
        for (int jj = 0; jj < 8; ++jj) o[jj] = Vs[(c * 8 + jj) * 68 + d];
        *(halfx8*)(dst + d * KT + ((c ^ (d & 7)) * 8)) = o;
    }
}

// ---------- main: phase A (sums + O) -> phase C (recompute S, write attn once) ----
// Wave decomposition: qh=wave>>2 (32 q-rows), kg=wave&3 (32 key-cols = 128B span).
// CRITICAL: each wave owns a FULL 128-B line of every mask/attn row it touches
// (two adjacent 64-B accesses, same wave, back-to-back). The 16-key/wave layout
// of rounds 2-4 split lines across waves -> L2 eviction between halves ->
// ~4x HBM RMW amplification (FETCH/WRITE 2.1 GB). Round 0 (128B/wave) had none.
__global__ __launch_bounds__(NT, 6) void sdpa_fused(
    const _Float16* __restrict__ kb,
    const _Float16* __restrict__ vtb,
    const float*    __restrict__ q,
    const int*      __restrict__ mask,
    float* __restrict__ out,
    float* __restrict__ attn)
{
    const int bid0 = blockIdx.x;                 // 1024
    const int bid  = (bid0 & 7) * 128 + (bid0 >> 3);   // XCD swizzle (1024%8==0)
    const int bn   = bid >> 5;                   // head 0..31
    const int qt   = bid & 31;
    const int row0 = qt * MT;
    const int tid  = threadIdx.x;
    const int wave = tid >> 6;                   // 0..7
    const int lane = tid & 63;
    const int lq   = lane & 15;
    const int lg   = lane >> 4;
    const int swz  = lq & 7;
    const int qh   = wave >> 2;                  // q-half: rows [qh*32, +32)
    const int kg   = wave & 3;                   // key group: cols [kg*32, +32)

    __shared__ __align__(16) char smem[49152];   // 48 KB -> 3 blocks/CU
    _Float16* Kb = (_Float16*)smem;              // 128 keys x 64 d  (16 KB)
    _Float16* Vb = (_Float16*)(smem + 16384);    // 64 d x 128 keys  (16 KB)
    _Float16* Ps = (_Float16*)(smem + 32768);    // 64 q x 128 keys  (16 KB)
    _Float16* Qt = Ps;                           // prologue alias (8 KB)
    float* sums_w = (float*)(smem + 32768);      // [8][32] post-loop alias
    float* inv_l  = (float*)(smem + 32768 + 1024);

    const _Float16* kh = kb  + (size_t)bn * (L * D);
    const _Float16* vh = vtb + (size_t)bn * (L * D);
    const int*      mg = mask + ((size_t)bn * L + row0) * L;
    float*          ag = attn + ((size_t)bn * L + row0) * L;

    // ---- prologue: convert this block's 64 Q rows to f16 (swizzled) ----
    {
        const int r = tid >> 3, c = tid & 7;     // 64 rows x 8 chunks
        const float4* s4 = (const float4*)(q + ((size_t)bn * L + row0 + r) * D + c * 8);
        float4 a = s4[0], b = s4[1];
        halfx8 t;
        t[0]=(_Float16)a.x; t[1]=(_Float16)a.y; t[2]=(_Float16)a.z; t[3]=(_Float16)a.w;
        t[4]=(_Float16)b.x; t[5]=(_Float16)b.y; t[6]=(_Float16)b.z; t[7]=(_Float16)b.w;
        *(halfx8*)(Qt + r * D + ((c ^ (r & 7)) * 8)) = t;
    }
    __syncthreads();
    halfx8 qf[2][2];                             // only this wave's q-half
    #pragma unroll
    for (int qq = 0; qq < 2; ++qq)
        #pragma unroll
        for (int s = 0; s < 2; ++s)
            qf[qq][s] = *(const halfx8*)(Qt + (qh*32 + qq*16 + lq) * D + (((s*4 + lg) ^ swz) * 8));
    __syncthreads();   // Qt reads done before Ps reuse

    f32x4 of[2] = {};
    float sumreg[2] = {0.f, 0.f};
    unsigned long long mpack[4] = {0ull, 0ull, 0ull, 0ull};  // [kk*2+qq], 16 tiles x 4 bits

    // prefetch tile 0
    halfx8 kr0 = *(const halfx8*)(kh + tid * 8);
    halfx8 kr1 = *(const halfx8*)(kh + (NT + tid) * 8);
    halfx8 vr0 = *(const halfx8*)(vh + tid * 8);
    halfx8 vr1 = *(const halfx8*)(vh + (NT + tid) * 8);
    i32x4 m4[2][2], m4n[2][2];
    #pragma unroll
    for (int qq = 0; qq < 2; ++qq)
        #pragma unroll
        for (int kk = 0; kk < 2; ++kk)
            m4[kk][qq] = *(const i32x4*)(mg + (size_t)(qh*32 + qq*16 + lq) * L
                                            + kg*32 + kk*16 + lg*4);

    // ================= PHASE A: sums + O =================
    #pragma unroll 2
    for (int t = 0; t < NTILE; ++t) {
        const int kb0 = t * KT;
        __syncthreads();                          // B0: prev tile LDS readers done
        *(halfx8*)(Kb + tid * 8)        = kr0;
        *(halfx8*)(Kb + (NT + tid) * 8) = kr1;
        *(halfx8*)(Vb + tid * 8)        = vr0;
        *(halfx8*)(Vb + (NT + tid) * 8) = vr1;
        __syncthreads();                          // B1: tiles staged
        if (t + 1 < NTILE) {                      // prefetch t+1 (lands during compute)
            const _Float16* ks = kh + (size_t)(kb0 + KT) * D;
            const _Float16* vs = vh + (size_t)(t + 1) * (KT * D);
            kr0 = *(const halfx8*)(ks + tid * 8);
            kr1 = *(const halfx8*)(ks + (NT + tid) * 8);
            vr0 = *(const halfx8*)(vs + tid * 8);
            vr1 = *(const halfx8*)(vs + (NT + tid) * 8);
            #pragma unroll
            for (int qq = 0; qq < 2; ++qq)
                #pragma unroll
                for (int kk = 0; kk < 2; ++kk)
                    m4n[kk][qq] = *(const i32x4*)(mg + (size_t)(qh*32 + qq*16 + lq) * L
                                                     + (kb0 + KT) + kg*32 + kk*16 + lg*4);
        }

        // S^T tile: wave owns keys [kg*32, +32), q rows [qh*32, +32)
        f32x4 acc[2][2] = {};                     // [kk][qq]
        __builtin_amdgcn_s_setprio(1);
        #pragma unroll
        for (int s = 0; s < 2; ++s) {
            halfx8 a0 = *(const halfx8*)(Kb + (kg*32 + lq)      * D + (((s*4 + lg) ^ swz) * 8));
            halfx8 a1 = *(const halfx8*)(Kb + (kg*32 + 16 + lq) * D + (((s*4 + lg) ^ swz) * 8));
            acc[0][0] = MFMA16(a0, qf[0][s], acc[0][0], 0, 0, 0);
            acc[0][1] = MFMA16(a0, qf[1][s], acc[0][1], 0, 0, 0);
            acc[1][0] = MFMA16(a1, qf[0][s], acc[1][0], 0, 0, 0);
            acc[1][1] = MFMA16(a1, qf[1][s], acc[1][1], 0, 0, 0);
        }
        __builtin_amdgcn_s_setprio(0);

        // mask -> pack bits; e = exp(S/8) -> Ps (f16) + fp32 row sums
        #pragma unroll
        for (int qq = 0; qq < 2; ++qq)
            #pragma unroll
            for (int kk = 0; kk < 2; ++kk) {
                const int qrow = qh*32 + qq*16 + lq;
                const int colL = kg*32 + kk*16 + lg*4;
                const i32x4 m = m4[kk][qq];
                const f32x4 a = acc[kk][qq];
                const unsigned mm = (m[0]?1u:0u) | (m[1]?2u:0u) | (m[2]?4u:0u) | (m[3]?8u:0u);
                mpack[kk*2+qq] |= (unsigned long long)mm << (t * 4);
                const float e0 = m[0] ? 0.f : __expf(a[0] * 0.125f);
                const float e1 = m[1] ? 0.f : __expf(a[1] * 0.125f);
                const float e2 = m[2] ? 0.f : __expf(a[2] * 0.125f);
                const float e3 = m[3] ? 0.f : __expf(a[3] * 0.125f);
                sumreg[qq] += (e0 + e1) + (e2 + e3);
                halfx4 pb;
                pb[0]=(_Float16)e0; pb[1]=(_Float16)e1; pb[2]=(_Float16)e2; pb[3]=(_Float16)e3;
                *(halfx4*)(Ps + qrow * KT + (colL ^ (swz << 3))) = pb;
            }
        if (t + 1 < NTILE) {
            #pragma unroll
            for (int qq = 0; qq < 2; ++qq)
                #pragma unroll
                for (int kk = 0; kk < 2; ++kk) m4[kk][qq] = m4n[kk][qq];
        }
        __syncthreads();                          // B2: Ps ready

        // O += Ps @ Vt ; wave: q-rows [qh*32,+32), d-cols [kg*16,+16)
        __builtin_amdgcn_s_setprio(1);
        #pragma unroll
        for (int s2 = 0; s2 < 4; ++s2) {
            const int ch = ((s2*4 + lg) ^ swz) * 8;
            halfx8 vb = *(const halfx8*)(Vb + (kg*16 + lq) * KT + ch);
            halfx8 p0 = *(const halfx8*)(Ps + (qh*32 + lq) * KT + ch);
            halfx8 p1 = *(const halfx8*)(Ps + (qh*32 + 16 + lq) * KT + ch);
            of[0] = MFMA16(p0, vb, of[0], 0, 0, 0);
            of[1] = MFMA16(p1, vb, of[1], 0, 0, 0);
        }
        __builtin_amdgcn_s_setprio(0);
    }

    // ---- row sums -> inv ----
    #pragma unroll
    for (int qq = 0; qq < 2; ++qq) {
        sumreg[qq] += __shfl_xor(sumreg[qq], 16, 64);
        sumreg[qq] += __shfl_xor(sumreg[qq], 32, 64);
    }
    __syncthreads();                              // last PV reads of Ps done
    if (lane < 16) {
        #pragma unroll
        for (int qq = 0; qq < 2; ++qq)
            sums_w[wave * 32 + qq*16 + lane] = sumreg[qq];
    }
    __syncthreads();
    if (tid < MT) {
        const int qh_t = tid >> 5, r = tid & 31;
        float s = 0.f;
        #pragma unroll
        for (int g = 0; g < 4; ++g) s += sums_w[(qh_t*4 + g) * 32 + r];
        inv_l[tid] = 1.0f / s;
    }
    __syncthreads();

    // per-lane inv for the S^T layout (row = qh*32 + qq*16 + lq)
    float invq[2];
    #pragma unroll
    for (int qq = 0; qq < 2; ++qq) invq[qq] = inv_l[qh*32 + qq*16 + lq];

    // phase-C prefetch tile 0 K (issue early, lands during O epilogue)
    kr0 = *(const halfx8*)(kh + tid * 8);
    kr1 = *(const halfx8*)(kh + (NT + tid) * 8);

    // ---- O epilogue (scaled) ----
    #pragma unroll
    for (int r = 0; r < 2; ++r)
        #pragma unroll
        for (int i = 0; i < 4; ++i) {
            const int qrow = qh*32 + r*16 + lg*4 + i;
            out[((size_t)bn * L + row0 + qrow) * D + kg*16 + lq] = of[r][i] * inv_l[qrow];
        }

    // ================= PHASE C: recompute S, write normalized attn once ======
    #pragma unroll 2
    for (int t = 0; t < NTILE; ++t) {
        const int kb0 = t * KT;
        __syncthreads();                          // prev tile Kb readers done
        *(halfx8*)(Kb + tid * 8)        = kr0;
        *(halfx8*)(Kb + (NT + tid) * 8) = kr1;
        __syncthreads();                          // K staged
        if (t + 1 < NTILE) {
            const _Float16* ks = kh + (size_t)(kb0 + KT) * D;
            kr0 = *(const halfx8*)(ks + tid * 8);
            kr1 = *(const halfx8*)(ks + (NT + tid) * 8);
        }

        f32x4 acc[2][2] = {};
        __builtin_amdgcn_s_setprio(1);
        #pragma unroll
        for (int s = 0; s < 2; ++s) {
            halfx8 a0 = *(const halfx8*)(Kb + (kg*32 + lq)      * D + (((s*4 + lg) ^ swz) * 8));
            halfx8 a1 = *(const halfx8*)(Kb + (kg*32 + 16 + lq) * D + (((s*4 + lg) ^ swz) * 8));
            acc[0][0] = MFMA16(a0, qf[0][s], acc[0][0], 0, 0, 0);
            acc[0][1] = MFMA16(a0, qf[1][s], acc[0][1], 0, 0, 0);
            acc[1][0] = MFMA16(a1, qf[0][s], acc[1][0], 0, 0, 0);
            acc[1][1] = MFMA16(a1, qf[1][s], acc[1][1], 0, 0, 0);
        }
        __builtin_amdgcn_s_setprio(0);

        // store: kk inner -> the wave's two 64-B halves of each 128-B line
        // are back-to-back in program order
        #pragma unroll
        for (int qq = 0; qq < 2; ++qq) {
            const float inv = invq[qq];
            float* rowp = ag + (size_t)(qh*32 + qq*16 + lq) * L + kb0 + kg*32 + lg*4;
            #pragma unroll
            for (int kk = 0; kk < 2; ++kk) {
                const unsigned mm = (unsigned)(mpack[kk*2+qq] >> (t * 4)) & 15u;
                const f32x4 a = acc[kk][qq];
                f32x4 ev;
                ev[0] = (mm & 1u) ? 0.f : __expf(a[0] * 0.125f) * inv;
                ev[1] = (mm & 2u) ? 0.f : __expf(a[1] * 0.125f) * inv;
                ev[2] = (mm & 4u) ? 0.f : __expf(a[2] * 0.125f) * inv;
                ev[3] = (mm & 8u) ? 0.f : __expf(a[3] * 0.125f) * inv;
                *(f32x4*)(rowp + kk*16) = ev;
            }
        }
    }
}

extern "C" void kernel_launch(void* const* d_in, const int* in_sizes, int n_in,
                              void* d_out, int out_size, void* d_ws, size_t ws_size,
                              hipStream_t stream) {
    const float* q    = (const float*)d_in[0];
    const float* k    = (const float*)d_in[1];
    const float* v    = (const float*)d_in[2];
    const int*   mask = (const int*)d_in[3];

    float* out = (float*)d_out;
    const int rows = in_sizes[0] / D;              // B*N*L = 65536
    float* attn = out + (size_t)rows * D;

    // workspace: kb | vtb (f16) = ~16.8 MB
    _Float16* kbuf = (_Float16*)d_ws;
    _Float16* vtb  = kbuf + (size_t)rows * D;

    conv_swz<<<rows * 8 / CNT, CNT, 0, stream>>>(k, kbuf, rows);
    vtrans<<<(rows / L) * NTILE, CNT, 0, stream>>>(v, vtb);
    sdpa_fused<<<rows / MT, NT, 0, stream>>>(kbuf, vtb, q, mask, out, attn);
}